// Round 1
// baseline (394.174 us; speedup 1.0000x reference)
//
#include <hip/hip_runtime.h>
#include <math.h>

// Problem constants
#define B_  4
#define T_  2048
#define H_  1024
#define NH_ 16
#define HD_ 64
// GEMM: M = B_*T_ = 8192, N = H_ = 1024, K = H_ = 1024

typedef __bf16  bf16x8  __attribute__((ext_vector_type(8)));
typedef float   f32x4   __attribute__((ext_vector_type(4)));
typedef unsigned short ushort8v __attribute__((ext_vector_type(8)));

__device__ __forceinline__ unsigned short f2bf(float f) {
    unsigned int u = __builtin_bit_cast(unsigned int, f);
    u += 0x7fffu + ((u >> 16) & 1u);   // round-to-nearest-even
    return (unsigned short)(u >> 16);
}

// ---------------------------------------------------------------------------
// fp32 -> bf16 conversion, 8 elements/thread, grid-stride
// n8 = element_count / 8
__global__ void cvt_f32_bf16(const float* __restrict__ in,
                             unsigned short* __restrict__ out, int n8) {
    int stride = gridDim.x * blockDim.x;
    for (int i = blockIdx.x * blockDim.x + threadIdx.x; i < n8; i += stride) {
        const float4* p = reinterpret_cast<const float4*>(in) + (size_t)i * 2;
        float4 f0 = p[0], f1 = p[1];
        ushort8v o;
        o[0] = f2bf(f0.x); o[1] = f2bf(f0.y); o[2] = f2bf(f0.z); o[3] = f2bf(f0.w);
        o[4] = f2bf(f1.x); o[5] = f2bf(f1.y); o[6] = f2bf(f1.z); o[7] = f2bf(f1.w);
        reinterpret_cast<ushort8v*>(out)[i] = o;
    }
}

// ---------------------------------------------------------------------------
// QKV projection GEMM: C[m][n] = sum_k X[m][k] * W[n][k] + bias[n]
// X: [8192][1024] bf16 row-major, W: [1024][1024] bf16 row-major (torch W, so
// this computes X @ W.T).
// MODE 0: out[((b*NH+h)*T + t)*HD + d]   (Q, K layout)
// MODE 2: out[((b*NH+h)*HD + d)*T + t]   (V transposed: [b][h][d][t])
// Tile: 128x128, BK=64, 4 waves (2x2), each wave 64x64 via 4x4 16x16 frags.
template <int MODE>
__global__ __launch_bounds__(256) void qkv_gemm(
    const unsigned short* __restrict__ X,
    const unsigned short* __restrict__ W,
    const float* __restrict__ bias,
    unsigned short* __restrict__ out)
{
    const int K = 1024;
    const int t    = threadIdx.x;
    const int lane = t & 63;
    const int wid  = t >> 6;
    const int lo = lane & 15, hi = lane >> 4;
    const int wm = wid >> 1, wn = wid & 1;
    const int m0 = blockIdx.y * 128;
    const int n0 = blockIdx.x * 128;

    __shared__ unsigned short As[128 * 72];
    __shared__ unsigned short Bs[128 * 72];

    f32x4 acc[4][4];
#pragma unroll
    for (int i = 0; i < 4; ++i)
#pragma unroll
        for (int j = 0; j < 4; ++j) acc[i][j] = (f32x4){0.f, 0.f, 0.f, 0.f};

    for (int k0 = 0; k0 < K; k0 += 64) {
        __syncthreads();
#pragma unroll
        for (int p = 0; p < 4; ++p) {
            int idx = (p * 256 + t) * 8;          // 0..8191
            int row = idx >> 6, col = idx & 63;
            *reinterpret_cast<ushort8v*>(&As[row * 72 + col]) =
                *reinterpret_cast<const ushort8v*>(&X[(size_t)(m0 + row) * K + k0 + col]);
            *reinterpret_cast<ushort8v*>(&Bs[row * 72 + col]) =
                *reinterpret_cast<const ushort8v*>(&W[(size_t)(n0 + row) * K + k0 + col]);
        }
        __syncthreads();
#pragma unroll
        for (int ks = 0; ks < 2; ++ks) {
            bf16x8 a[4], b[4];
#pragma unroll
            for (int mt = 0; mt < 4; ++mt)
                a[mt] = *reinterpret_cast<const bf16x8*>(
                    &As[(wm * 64 + mt * 16 + lo) * 72 + ks * 32 + hi * 8]);
#pragma unroll
            for (int nt = 0; nt < 4; ++nt)
                b[nt] = *reinterpret_cast<const bf16x8*>(
                    &Bs[(wn * 64 + nt * 16 + lo) * 72 + ks * 32 + hi * 8]);
#pragma unroll
            for (int mt = 0; mt < 4; ++mt)
#pragma unroll
                for (int nt = 0; nt < 4; ++nt)
                    acc[mt][nt] = __builtin_amdgcn_mfma_f32_16x16x32_bf16(
                        a[mt], b[nt], acc[mt][nt], 0, 0, 0);
        }
    }

    // Epilogue: D layout row=(lane>>4)*4+r, col=lane&15
#pragma unroll
    for (int nt = 0; nt < 4; ++nt) {
        int n = n0 + wn * 64 + nt * 16 + lo;
        float bv = bias[n];
        int h = n >> 6, d = n & 63;
#pragma unroll
        for (int mt = 0; mt < 4; ++mt) {
            int mbase = m0 + wm * 64 + mt * 16 + hi * 4;   // 4 consecutive m
            int bb = mbase >> 11;
            int tt = mbase & 2047;
            if (MODE == 2) {
                // pack 4 consecutive t at fixed d -> one 8B store
                ushort4 pk;
                pk.x = f2bf(acc[mt][nt][0] + bv);
                pk.y = f2bf(acc[mt][nt][1] + bv);
                pk.z = f2bf(acc[mt][nt][2] + bv);
                pk.w = f2bf(acc[mt][nt][3] + bv);
                size_t addr = ((size_t)(bb * NH_ + h) * HD_ + d) * T_ + tt;
                *reinterpret_cast<ushort4*>(&out[addr]) = pk;
            } else {
                size_t base = (size_t)(bb * NH_ + h) * T_;
#pragma unroll
                for (int r = 0; r < 4; ++r)
                    out[(base + tt + r) * HD_ + d] = f2bf(acc[mt][nt][r] + bv);
            }
        }
    }
}

// ---------------------------------------------------------------------------
// Causal flash attention forward.
// Q,K: [B*NH][T][HD] bf16. Vt: [B*NH][HD][T] bf16. amask: [B][T] fp32 additive.
// out: [B][T][H] fp32.
// One block per (b, h, 64-row q-tile). 4 waves, each owns 16 q-rows.
__global__ __launch_bounds__(256) void attn_fwd(
    const unsigned short* __restrict__ Q,
    const unsigned short* __restrict__ Kb,
    const unsigned short* __restrict__ Vt,
    const float* __restrict__ amask,
    float* __restrict__ out)
{
    const int t    = threadIdx.x;
    const int lane = t & 63;
    const int w    = t >> 6;
    const int lo = lane & 15, hi = lane >> 4;

    int bid = blockIdx.x;
    int qt = bid & 31;
    int h  = (bid >> 5) & 15;
    int b  = bid >> 9;
    int bh = b * NH_ + h;
    int qbase = qt * 64;

    __shared__ unsigned short Qs[64 * 72];
    __shared__ unsigned short Ks[64 * 72];
    __shared__ unsigned short Vs[64 * 72];     // Vt tile: [d][kv]
    __shared__ unsigned short Ps[4][16 * 72];  // per-wave P strip [16 rows][kv]

    // stage Q tile
    const unsigned short* Qg = Q + (size_t)bh * T_ * HD_ + (size_t)qbase * HD_;
#pragma unroll
    for (int p = 0; p < 2; ++p) {
        int idx = (p * 256 + t) * 8;           // 0..4095
        int row = idx >> 6, col = idx & 63;
        *reinterpret_cast<ushort8v*>(&Qs[row * 72 + col]) =
            *reinterpret_cast<const ushort8v*>(&Qg[row * 64 + col]);
    }

    f32x4 o[4];
#pragma unroll
    for (int dt = 0; dt < 4; ++dt) o[dt] = (f32x4){0.f, 0.f, 0.f, 0.f};
    float m_i[4], l_i[4];
#pragma unroll
    for (int r = 0; r < 4; ++r) { m_i[r] = -INFINITY; l_i[r] = 0.f; }

    const float* am = amask + (size_t)b * T_;

    for (int kt = 0; kt <= qt; ++kt) {
        int kvbase = kt * 64;
        __syncthreads();   // protect Ks/Vs until all waves finished previous PV
        const unsigned short* Kg = Kb + (size_t)bh * T_ * HD_ + (size_t)kvbase * HD_;
        const unsigned short* Vg = Vt + (size_t)bh * HD_ * T_ + kvbase;
#pragma unroll
        for (int p = 0; p < 2; ++p) {
            int idx = (p * 256 + t) * 8;
            int row = idx >> 6, col = idx & 63;
            *reinterpret_cast<ushort8v*>(&Ks[row * 72 + col]) =
                *reinterpret_cast<const ushort8v*>(&Kg[row * 64 + col]);
            *reinterpret_cast<ushort8v*>(&Vs[row * 72 + col]) =
                *reinterpret_cast<const ushort8v*>(&Vg[(size_t)row * T_ + col]);
        }
        __syncthreads();

        // S = Q K^T for this wave's 16 rows; 4 col-tiles of 16
        f32x4 s[4];
#pragma unroll
        for (int ct = 0; ct < 4; ++ct) s[ct] = (f32x4){0.f, 0.f, 0.f, 0.f};
#pragma unroll
        for (int ks = 0; ks < 2; ++ks) {
            bf16x8 aq = *reinterpret_cast<const bf16x8*>(
                &Qs[(w * 16 + lo) * 72 + ks * 32 + hi * 8]);
#pragma unroll
            for (int ct = 0; ct < 4; ++ct) {
                bf16x8 bk = *reinterpret_cast<const bf16x8*>(
                    &Ks[(ct * 16 + lo) * 72 + ks * 32 + hi * 8]);
                s[ct] = __builtin_amdgcn_mfma_f32_16x16x32_bf16(aq, bk, s[ct], 0, 0, 0);
            }
        }

        // online softmax; lane holds S[qrow = w*16 + hi*4 + r][kv = ct*16 + lo]
        float pv[4][4];   // [ct][r]
#pragma unroll
        for (int r = 0; r < 4; ++r) {
            int qg = qbase + w * 16 + hi * 4 + r;
            float vals[4];
            float rowmax = -INFINITY;
#pragma unroll
            for (int ct = 0; ct < 4; ++ct) {
                int kg = kvbase + ct * 16 + lo;
                float v = s[ct][r] * 0.125f + am[kg];
                if (kg > qg) v = -INFINITY;
                vals[ct] = v;
                rowmax = fmaxf(rowmax, v);
            }
#pragma unroll
            for (int msk = 1; msk < 16; msk <<= 1)
                rowmax = fmaxf(rowmax, __shfl_xor(rowmax, msk, 64));
            float mnew = fmaxf(m_i[r], rowmax);
            float corr = expf(m_i[r] - mnew);   // first tile: exp(-inf)=0
            float rsum = 0.f;
#pragma unroll
            for (int ct = 0; ct < 4; ++ct) {
                float p = expf(vals[ct] - mnew);
                pv[ct][r] = p;
                rsum += p;
            }
#pragma unroll
            for (int msk = 1; msk < 16; msk <<= 1)
                rsum += __shfl_xor(rsum, msk, 64);
            l_i[r] = l_i[r] * corr + rsum;
            m_i[r] = mnew;
#pragma unroll
            for (int dt = 0; dt < 4; ++dt) o[dt][r] *= corr;
        }

        // stage P (bf16) into this wave's private strip
#pragma unroll
        for (int ct = 0; ct < 4; ++ct)
#pragma unroll
            for (int r = 0; r < 4; ++r)
                Ps[w][(hi * 4 + r) * 72 + ct * 16 + lo] = f2bf(pv[ct][r]);
        __syncthreads();   // also drains LDS so wave sees its own strip

        // O += P @ V   (B-operand from Vt, same Bt fragment pattern)
#pragma unroll
        for (int ks = 0; ks < 2; ++ks) {
            bf16x8 ap = *reinterpret_cast<const bf16x8*>(
                &Ps[w][lo * 72 + ks * 32 + hi * 8]);
#pragma unroll
            for (int dt = 0; dt < 4; ++dt) {
                bf16x8 bv = *reinterpret_cast<const bf16x8*>(
                    &Vs[(dt * 16 + lo) * 72 + ks * 32 + hi * 8]);
                o[dt] = __builtin_amdgcn_mfma_f32_16x16x32_bf16(ap, bv, o[dt], 0, 0, 0);
            }
        }
    }

    // epilogue: out[b][t][h*64 + d] = o / l
#pragma unroll
    for (int r = 0; r < 4; ++r) {
        int tt = qbase + w * 16 + hi * 4 + r;
        float inv = 1.0f / l_i[r];
        float* orow = out + ((size_t)b * T_ + tt) * H_ + h * HD_;
#pragma unroll
        for (int dt = 0; dt < 4; ++dt)
            orow[dt * 16 + lo] = o[dt][r] * inv;
    }
}

// ---------------------------------------------------------------------------
extern "C" void kernel_launch(void* const* d_in, const int* in_sizes, int n_in,
                              void* d_out, int out_size, void* d_ws, size_t ws_size,
                              hipStream_t stream) {
    const float* hs    = (const float*)d_in[0];   // [B,T,H]
    const float* amask = (const float*)d_in[1];   // [B,1,1,T]
    const float* Wq    = (const float*)d_in[2];
    const float* bq    = (const float*)d_in[3];
    const float* Wk    = (const float*)d_in[4];
    const float* bk    = (const float*)d_in[5];
    const float* Wv    = (const float*)d_in[6];
    const float* bv    = (const float*)d_in[7];
    float* out = (float*)d_out;

    // Workspace layout (bf16 elements). Total ~73.4 MB.
    unsigned short* Xbf = (unsigned short*)d_ws;          // 8192*1024
    unsigned short* Wqb = Xbf + (size_t)8192 * 1024;      // 1024*1024
    unsigned short* Wkb = Wqb + (size_t)1024 * 1024;
    unsigned short* Wvb = Wkb + (size_t)1024 * 1024;
    unsigned short* Qb  = Wvb + (size_t)1024 * 1024;      // [B*NH][T][HD]
    unsigned short* Kbf = Qb  + (size_t)B_ * NH_ * T_ * HD_;
    unsigned short* Vtb = Kbf + (size_t)B_ * NH_ * T_ * HD_;  // [B*NH][HD][T]

    // 1) fp32 -> bf16
    cvt_f32_bf16<<<4096, 256, 0, stream>>>(hs, Xbf, (8192 * 1024) / 8);
    cvt_f32_bf16<<<512, 256, 0, stream>>>(Wq, Wqb, (1024 * 1024) / 8);
    cvt_f32_bf16<<<512, 256, 0, stream>>>(Wk, Wkb, (1024 * 1024) / 8);
    cvt_f32_bf16<<<512, 256, 0, stream>>>(Wv, Wvb, (1024 * 1024) / 8);

    // 2) QKV projections
    dim3 g(8, 64);   // N/128, M/128
    qkv_gemm<0><<<g, 256, 0, stream>>>(Xbf, Wqb, bq, Qb);
    qkv_gemm<0><<<g, 256, 0, stream>>>(Xbf, Wkb, bk, Kbf);
    qkv_gemm<2><<<g, 256, 0, stream>>>(Xbf, Wvb, bv, Vtb);

    // 3) causal flash attention
    attn_fwd<<<2048, 256, 0, stream>>>(Qb, Kbf, Vtb, amask, out);
}

// Round 2
// 386.957 us; speedup vs baseline: 1.0186x; 1.0186x over previous
//
#include <hip/hip_runtime.h>
#include <math.h>

// Problem constants
#define B_  4
#define T_  2048
#define H_  1024
#define NH_ 16
#define HD_ 64
// GEMM: M = B_*T_ = 8192, N = H_ = 1024, K = H_ = 1024

typedef __bf16  bf16x8  __attribute__((ext_vector_type(8)));
typedef float   f32x4   __attribute__((ext_vector_type(4)));
typedef unsigned short ushort8v __attribute__((ext_vector_type(8)));
typedef short   short4v __attribute__((ext_vector_type(4)));

__device__ __forceinline__ unsigned short f2bf(float f) {
    unsigned int u = __builtin_bit_cast(unsigned int, f);
    u += 0x7fffu + ((u >> 16) & 1u);   // round-to-nearest-even
    return (unsigned short)(u >> 16);
}

// 16x16x16 bf16 MFMA (K=16): A/B are 4 bf16 (2 VGPRs) with k=(lane>>4)*4+j.
__device__ __forceinline__ f32x4 mfma16x16x16bf16(short4v a, short4v b, f32x4 c) {
#if __has_builtin(__builtin_amdgcn_mfma_f32_16x16x16bf16_1k)
    return __builtin_amdgcn_mfma_f32_16x16x16bf16_1k(a, b, c, 0, 0, 0);
#else
    f32x4 d = c;
    asm volatile("v_mfma_f32_16x16x16_bf16 %0, %1, %2, %0\n\ts_nop 7\n\ts_nop 7"
                 : "+v"(d) : "v"(a), "v"(b));
    return d;
#endif
}

// ---------------------------------------------------------------------------
// fp32 -> bf16 conversion, 8 elements/thread, grid-stride
__global__ void cvt_f32_bf16(const float* __restrict__ in,
                             unsigned short* __restrict__ out, int n8) {
    int stride = gridDim.x * blockDim.x;
    for (int i = blockIdx.x * blockDim.x + threadIdx.x; i < n8; i += stride) {
        const float4* p = reinterpret_cast<const float4*>(in) + (size_t)i * 2;
        float4 f0 = p[0], f1 = p[1];
        ushort8v o;
        o[0] = f2bf(f0.x); o[1] = f2bf(f0.y); o[2] = f2bf(f0.z); o[3] = f2bf(f0.w);
        o[4] = f2bf(f1.x); o[5] = f2bf(f1.y); o[6] = f2bf(f1.z); o[7] = f2bf(f1.w);
        reinterpret_cast<ushort8v*>(out)[i] = o;
    }
}

// ---------------------------------------------------------------------------
// QKV projection GEMM: C[m][n] = sum_k X[m][k] * W[n][k] + bias[n]
// MODE 0: out[((b*NH+h)*T + t)*HD + d]   (Q, K layout)
// MODE 2: out[((b*NH+h)*HD + d)*T + t]   (V transposed: [b][h][d][t])
template <int MODE>
__global__ __launch_bounds__(256) void qkv_gemm(
    const unsigned short* __restrict__ X,
    const unsigned short* __restrict__ W,
    const float* __restrict__ bias,
    unsigned short* __restrict__ out)
{
    const int K = 1024;
    const int t    = threadIdx.x;
    const int lane = t & 63;
    const int wid  = t >> 6;
    const int lo = lane & 15, hi = lane >> 4;
    const int wm = wid >> 1, wn = wid & 1;
    const int m0 = blockIdx.y * 128;
    const int n0 = blockIdx.x * 128;

    __shared__ unsigned short As[128 * 72];
    __shared__ unsigned short Bs[128 * 72];

    f32x4 acc[4][4];
#pragma unroll
    for (int i = 0; i < 4; ++i)
#pragma unroll
        for (int j = 0; j < 4; ++j) acc[i][j] = (f32x4){0.f, 0.f, 0.f, 0.f};

    for (int k0 = 0; k0 < K; k0 += 64) {
        __syncthreads();
#pragma unroll
        for (int p = 0; p < 4; ++p) {
            int idx = (p * 256 + t) * 8;          // 0..8191
            int row = idx >> 6, col = idx & 63;
            *reinterpret_cast<ushort8v*>(&As[row * 72 + col]) =
                *reinterpret_cast<const ushort8v*>(&X[(size_t)(m0 + row) * K + k0 + col]);
            *reinterpret_cast<ushort8v*>(&Bs[row * 72 + col]) =
                *reinterpret_cast<const ushort8v*>(&W[(size_t)(n0 + row) * K + k0 + col]);
        }
        __syncthreads();
#pragma unroll
        for (int ks = 0; ks < 2; ++ks) {
            bf16x8 a[4], b[4];
#pragma unroll
            for (int mt = 0; mt < 4; ++mt)
                a[mt] = *reinterpret_cast<const bf16x8*>(
                    &As[(wm * 64 + mt * 16 + lo) * 72 + ks * 32 + hi * 8]);
#pragma unroll
            for (int nt = 0; nt < 4; ++nt)
                b[nt] = *reinterpret_cast<const bf16x8*>(
                    &Bs[(wn * 64 + nt * 16 + lo) * 72 + ks * 32 + hi * 8]);
#pragma unroll
            for (int mt = 0; mt < 4; ++mt)
#pragma unroll
                for (int nt = 0; nt < 4; ++nt)
                    acc[mt][nt] = __builtin_amdgcn_mfma_f32_16x16x32_bf16(
                        a[mt], b[nt], acc[mt][nt], 0, 0, 0);
        }
    }

#pragma unroll
    for (int nt = 0; nt < 4; ++nt) {
        int n = n0 + wn * 64 + nt * 16 + lo;
        float bv = bias[n];
        int h = n >> 6, d = n & 63;
#pragma unroll
        for (int mt = 0; mt < 4; ++mt) {
            int mbase = m0 + wm * 64 + mt * 16 + hi * 4;
            int bb = mbase >> 11;
            int tt = mbase & 2047;
            if (MODE == 2) {
                ushort4 pk;
                pk.x = f2bf(acc[mt][nt][0] + bv);
                pk.y = f2bf(acc[mt][nt][1] + bv);
                pk.z = f2bf(acc[mt][nt][2] + bv);
                pk.w = f2bf(acc[mt][nt][3] + bv);
                size_t addr = ((size_t)(bb * NH_ + h) * HD_ + d) * T_ + tt;
                *reinterpret_cast<ushort4*>(&out[addr]) = pk;
            } else {
                size_t base = (size_t)(bb * NH_ + h) * T_;
#pragma unroll
                for (int r = 0; r < 4; ++r)
                    out[(base + tt + r) * HD_ + d] = f2bf(acc[mt][nt][r] + bv);
            }
        }
    }
}

// ---------------------------------------------------------------------------
// Causal flash attention, barrier-free / LDS-free.
// Q,K: [B*NH][T][HD] bf16. Vt: [B*NH][HD][T] bf16. amask: [B][T] fp32.
// out: [B][T][H] fp32.
// Grid: 1024 blocks (XCD-swizzled over (bh, qchunk)); 4 independent waves per
// block; each wave owns 32 q-rows.
// Swapped QK^T: S^T = mfma(K, Q)  -> lane holds q = lane&15, kv-local = hi*4+r.
// Swapped PV:   O^T = mfma(Vt, P^T) with 16x16x16 (k = hi*4+j matches kv-local
// layout exactly -> P never leaves the lane).
__global__ __launch_bounds__(256, 2) void attn_fwd2(
    const unsigned short* __restrict__ Q,
    const unsigned short* __restrict__ Kb,
    const unsigned short* __restrict__ Vt,
    const float* __restrict__ amask,
    float* __restrict__ out)
{
    const int lane = threadIdx.x & 63;
    const int w    = threadIdx.x >> 6;
    const int lo = lane & 15, hi = lane >> 4;

    // bijective XCD swizzle: 8 heads per XCD (K+V = 4MB = one L2)
    const int bid  = blockIdx.x;
    const int xcd  = bid & 7;
    const int slot = bid >> 3;            // 0..127
    const int bh   = xcd * 8 + (slot >> 4);
    const int qc   = slot & 15;
    const int b    = bh >> 4;
    const int h    = bh & 15;
    const int q0   = qc * 128 + w * 32;

    const unsigned short* Qg = Q  + (size_t)bh * T_ * HD_;
    const unsigned short* Kg = Kb + (size_t)bh * T_ * HD_;
    const unsigned short* Vg = Vt + (size_t)bh * HD_ * T_;
    const float* am = amask + (size_t)b * T_;

    // Q fragments (B-operand of swapped QK^T): col=q=mt*16+lo, k=ks*32+hi*8+j
    bf16x8 qf[2][2];
#pragma unroll
    for (int mt = 0; mt < 2; ++mt)
#pragma unroll
        for (int ks = 0; ks < 2; ++ks)
            qf[mt][ks] = *reinterpret_cast<const bf16x8*>(
                &Qg[(size_t)(q0 + mt * 16 + lo) * HD_ + ks * 32 + hi * 8]);

    f32x4 o[2][4];
#pragma unroll
    for (int mt = 0; mt < 2; ++mt)
#pragma unroll
        for (int dt = 0; dt < 4; ++dt) o[mt][dt] = (f32x4){0.f, 0.f, 0.f, 0.f};
    float m_r[2] = {-INFINITY, -INFINITY};
    float l_r[2] = {0.f, 0.f};

    const float SC    = 0.125f * 1.44269504089f;   // scale * log2(e)
    const float LOG2E = 1.44269504089f;

    const int nt = (q0 >> 6) + 1;
    for (int kt = 0; kt < nt; ++kt) {
        const int kv0 = kt * 64;

        // K A-frags: row=kv=ct*16+lo, k=ks*32+hi*8+j  (16B loads)
        bf16x8 kf[4][2];
#pragma unroll
        for (int ct = 0; ct < 4; ++ct)
#pragma unroll
            for (int ks = 0; ks < 2; ++ks)
                kf[ct][ks] = *reinterpret_cast<const bf16x8*>(
                    &Kg[(size_t)(kv0 + ct * 16 + lo) * HD_ + ks * 32 + hi * 8]);

        // Vt A-frags (PV): row=d=dt*16+lo, k=kv-local=ct*16+hi*4+j (8B loads)
        short4v vf[4][4];
#pragma unroll
        for (int dt = 0; dt < 4; ++dt)
#pragma unroll
            for (int ct = 0; ct < 4; ++ct)
                vf[dt][ct] = *reinterpret_cast<const short4v*>(
                    &Vg[(size_t)(dt * 16 + lo) * T_ + kv0 + ct * 16 + hi * 4]);

        // additive mask values for this lane's kv slots
        f32x4 amv[4];
#pragma unroll
        for (int ct = 0; ct < 4; ++ct)
            amv[ct] = *reinterpret_cast<const f32x4*>(&am[kv0 + ct * 16 + hi * 4]);

        // S^T = K Q^T : lane holds S[kv0+ct*16+hi*4+r][q0+mt*16+lo]
        f32x4 s[2][4];
#pragma unroll
        for (int mt = 0; mt < 2; ++mt)
#pragma unroll
            for (int ct = 0; ct < 4; ++ct) s[mt][ct] = (f32x4){0.f, 0.f, 0.f, 0.f};
#pragma unroll
        for (int ks = 0; ks < 2; ++ks)
#pragma unroll
            for (int ct = 0; ct < 4; ++ct)
#pragma unroll
                for (int mt = 0; mt < 2; ++mt)
                    s[mt][ct] = __builtin_amdgcn_mfma_f32_16x16x32_bf16(
                        kf[ct][ks], qf[mt][ks], s[mt][ct], 0, 0, 0);

        const bool edge = (kv0 + 63 > q0);   // any lane's kv can exceed its q

        short4v p[2][4];
#pragma unroll
        for (int mt = 0; mt < 2; ++mt) {
            const int q = q0 + mt * 16 + lo;
            float mx = -INFINITY;
#pragma unroll
            for (int ct = 0; ct < 4; ++ct) {
#pragma unroll
                for (int r = 0; r < 4; ++r) {
                    float v = s[mt][ct][r] * SC + amv[ct][r] * LOG2E;
                    if (edge && (kv0 + ct * 16 + hi * 4 + r > q)) v = -INFINITY;
                    s[mt][ct][r] = v;
                    mx = fmaxf(mx, v);
                }
            }
            mx = fmaxf(mx, __shfl_xor(mx, 16, 64));
            mx = fmaxf(mx, __shfl_xor(mx, 32, 64));
            const float mnew = fmaxf(m_r[mt], mx);
            const float corr = exp2f(m_r[mt] - mnew);
            float rs = 0.f;
#pragma unroll
            for (int ct = 0; ct < 4; ++ct) {
                short4v pk;
#pragma unroll
                for (int r = 0; r < 4; ++r) {
                    float pe = exp2f(s[mt][ct][r] - mnew);
                    rs += pe;
                    pk[r] = (short)f2bf(pe);
                }
                p[mt][ct] = pk;
            }
            rs += __shfl_xor(rs, 16, 64);
            rs += __shfl_xor(rs, 32, 64);
            m_r[mt] = mnew;
            l_r[mt] = l_r[mt] * corr + rs;
#pragma unroll
            for (int dt = 0; dt < 4; ++dt) o[mt][dt] *= corr;
        }

        // O^T += V^T P^T : o[mt][dt] has col=q=lo, row=d=dt*16+hi*4+r
#pragma unroll
        for (int ct = 0; ct < 4; ++ct)
#pragma unroll
            for (int mt = 0; mt < 2; ++mt)
#pragma unroll
                for (int dt = 0; dt < 4; ++dt)
                    o[mt][dt] = mfma16x16x16bf16(vf[dt][ct], p[mt][ct], o[mt][dt]);
    }

    // epilogue: out[b][t=q][h*64 + d] = O^T[d][q] / l[q]
#pragma unroll
    for (int mt = 0; mt < 2; ++mt) {
        const int tq = q0 + mt * 16 + lo;
        const float inv = 1.0f / l_r[mt];
        float* orow = out + ((size_t)b * T_ + tq) * H_ + h * HD_;
#pragma unroll
        for (int dt = 0; dt < 4; ++dt) {
            f32x4 v = o[mt][dt] * inv;
            *reinterpret_cast<f32x4*>(&orow[dt * 16 + hi * 4]) = v;
        }
    }
}

// ---------------------------------------------------------------------------
extern "C" void kernel_launch(void* const* d_in, const int* in_sizes, int n_in,
                              void* d_out, int out_size, void* d_ws, size_t ws_size,
                              hipStream_t stream) {
    const float* hs    = (const float*)d_in[0];   // [B,T,H]
    const float* amask = (const float*)d_in[1];   // [B,1,1,T]
    const float* Wq    = (const float*)d_in[2];
    const float* bq    = (const float*)d_in[3];
    const float* Wk    = (const float*)d_in[4];
    const float* bk    = (const float*)d_in[5];
    const float* Wv    = (const float*)d_in[6];
    const float* bv    = (const float*)d_in[7];
    float* out = (float*)d_out;

    unsigned short* Xbf = (unsigned short*)d_ws;          // 8192*1024
    unsigned short* Wqb = Xbf + (size_t)8192 * 1024;
    unsigned short* Wkb = Wqb + (size_t)1024 * 1024;
    unsigned short* Wvb = Wkb + (size_t)1024 * 1024;
    unsigned short* Qb  = Wvb + (size_t)1024 * 1024;      // [B*NH][T][HD]
    unsigned short* Kbf = Qb  + (size_t)B_ * NH_ * T_ * HD_;
    unsigned short* Vtb = Kbf + (size_t)B_ * NH_ * T_ * HD_;  // [B*NH][HD][T]

    cvt_f32_bf16<<<4096, 256, 0, stream>>>(hs, Xbf, (8192 * 1024) / 8);
    cvt_f32_bf16<<<512, 256, 0, stream>>>(Wq, Wqb, (1024 * 1024) / 8);
    cvt_f32_bf16<<<512, 256, 0, stream>>>(Wk, Wkb, (1024 * 1024) / 8);
    cvt_f32_bf16<<<512, 256, 0, stream>>>(Wv, Wvb, (1024 * 1024) / 8);

    dim3 g(8, 64);   // N/128, M/128
    qkv_gemm<0><<<g, 256, 0, stream>>>(Xbf, Wqb, bq, Qb);
    qkv_gemm<0><<<g, 256, 0, stream>>>(Xbf, Wkb, bk, Kbf);
    qkv_gemm<2><<<g, 256, 0, stream>>>(Xbf, Wvb, bv, Vtb);

    attn_fwd2<<<1024, 256, 0, stream>>>(Qb, Kbf, Vtb, amask, out);
}

// Round 4
// 328.179 us; speedup vs baseline: 1.2011x; 1.1791x over previous
//
#include <hip/hip_runtime.h>
#include <math.h>

// Problem constants
#define B_  4
#define T_  2048
#define H_  1024
#define NH_ 16
#define HD_ 64

typedef __bf16  bf16x8  __attribute__((ext_vector_type(8)));
typedef float   f32x4   __attribute__((ext_vector_type(4)));
typedef unsigned short ushort8v __attribute__((ext_vector_type(8)));
typedef short   short4v __attribute__((ext_vector_type(4)));

__device__ __forceinline__ unsigned short f2bf(float f) {
    unsigned int u = __builtin_bit_cast(unsigned int, f);
    u += 0x7fffu + ((u >> 16) & 1u);
    return (unsigned short)(u >> 16);
}

// 16x16x16 bf16 MFMA (K=16): A/B k=(lane>>4)*4+j
__device__ __forceinline__ f32x4 mfma16x16x16bf16(short4v a, short4v b, f32x4 c) {
#if __has_builtin(__builtin_amdgcn_mfma_f32_16x16x16bf16_1k)
    return __builtin_amdgcn_mfma_f32_16x16x16bf16_1k(a, b, c, 0, 0, 0);
#else
    f32x4 d = c;
    asm volatile("v_mfma_f32_16x16x16_bf16 %0, %1, %2, %0\n\ts_nop 7\n\ts_nop 7"
                 : "+v"(d) : "v"(a), "v"(b));
    return d;
#endif
}

// ---------------------------------------------------------------------------
__global__ void cvt_f32_bf16(const float* __restrict__ in,
                             unsigned short* __restrict__ out, int n8) {
    int stride = gridDim.x * blockDim.x;
    for (int i = blockIdx.x * blockDim.x + threadIdx.x; i < n8; i += stride) {
        const float4* p = reinterpret_cast<const float4*>(in) + (size_t)i * 2;
        float4 f0 = p[0], f1 = p[1];
        ushort8v o;
        o[0] = f2bf(f0.x); o[1] = f2bf(f0.y); o[2] = f2bf(f0.z); o[3] = f2bf(f0.w);
        o[4] = f2bf(f1.x); o[5] = f2bf(f1.y); o[6] = f2bf(f1.z); o[7] = f2bf(f1.w);
        reinterpret_cast<ushort8v*>(out)[i] = o;
    }
}

// ---------------------------------------------------------------------------
// QKV projection GEMM (unchanged from R2)
template <int MODE>
__global__ __launch_bounds__(256) void qkv_gemm(
    const unsigned short* __restrict__ X,
    const unsigned short* __restrict__ W,
    const float* __restrict__ bias,
    unsigned short* __restrict__ out)
{
    const int K = 1024;
    const int t    = threadIdx.x;
    const int lane = t & 63;
    const int wid  = t >> 6;
    const int lo = lane & 15, hi = lane >> 4;
    const int wm = wid >> 1, wn = wid & 1;
    const int m0 = blockIdx.y * 128;
    const int n0 = blockIdx.x * 128;

    __shared__ unsigned short As[128 * 72];
    __shared__ unsigned short Bs[128 * 72];

    f32x4 acc[4][4];
#pragma unroll
    for (int i = 0; i < 4; ++i)
#pragma unroll
        for (int j = 0; j < 4; ++j) acc[i][j] = (f32x4){0.f, 0.f, 0.f, 0.f};

    for (int k0 = 0; k0 < K; k0 += 64) {
        __syncthreads();
#pragma unroll
        for (int p = 0; p < 4; ++p) {
            int idx = (p * 256 + t) * 8;
            int row = idx >> 6, col = idx & 63;
            *reinterpret_cast<ushort8v*>(&As[row * 72 + col]) =
                *reinterpret_cast<const ushort8v*>(&X[(size_t)(m0 + row) * K + k0 + col]);
            *reinterpret_cast<ushort8v*>(&Bs[row * 72 + col]) =
                *reinterpret_cast<const ushort8v*>(&W[(size_t)(n0 + row) * K + k0 + col]);
        }
        __syncthreads();
#pragma unroll
        for (int ks = 0; ks < 2; ++ks) {
            bf16x8 a[4], b[4];
#pragma unroll
            for (int mt = 0; mt < 4; ++mt)
                a[mt] = *reinterpret_cast<const bf16x8*>(
                    &As[(wm * 64 + mt * 16 + lo) * 72 + ks * 32 + hi * 8]);
#pragma unroll
            for (int nt = 0; nt < 4; ++nt)
                b[nt] = *reinterpret_cast<const bf16x8*>(
                    &Bs[(wn * 64 + nt * 16 + lo) * 72 + ks * 32 + hi * 8]);
#pragma unroll
            for (int mt = 0; mt < 4; ++mt)
#pragma unroll
                for (int nt = 0; nt < 4; ++nt)
                    acc[mt][nt] = __builtin_amdgcn_mfma_f32_16x16x32_bf16(
                        a[mt], b[nt], acc[mt][nt], 0, 0, 0);
        }
    }

#pragma unroll
    for (int nt = 0; nt < 4; ++nt) {
        int n = n0 + wn * 64 + nt * 16 + lo;
        float bv = bias[n];
        int h = n >> 6, d = n & 63;
#pragma unroll
        for (int mt = 0; mt < 4; ++mt) {
            int mbase = m0 + wm * 64 + mt * 16 + hi * 4;
            int bb = mbase >> 11;
            int tt = mbase & 2047;
            if (MODE == 2) {
                ushort4 pk;
                pk.x = f2bf(acc[mt][nt][0] + bv);
                pk.y = f2bf(acc[mt][nt][1] + bv);
                pk.z = f2bf(acc[mt][nt][2] + bv);
                pk.w = f2bf(acc[mt][nt][3] + bv);
                size_t addr = ((size_t)(bb * NH_ + h) * HD_ + d) * T_ + tt;
                *reinterpret_cast<ushort4*>(&out[addr]) = pk;
            } else {
                size_t base = (size_t)(bb * NH_ + h) * T_;
#pragma unroll
                for (int r = 0; r < 4; ++r)
                    out[(base + tt + r) * HD_ + d] = f2bf(acc[mt][nt][r] + bv);
            }
        }
    }
}

// ---------------------------------------------------------------------------
// Causal flash attention v4: R2-proven body + balanced pairing + K ping-pong.
// Each wave owns 32 q-rows (unit u), processes u then 63-u.
__device__ __forceinline__ void attn_unit(
    int u, int lo, int hi,
    const unsigned short* __restrict__ Qg,
    const unsigned short* __restrict__ Kg,
    const unsigned short* __restrict__ Vg,
    const float* __restrict__ am,
    float* __restrict__ outBase)
{
    const float SC    = 0.125f * 1.44269504089f;
    const float LOG2E = 1.44269504089f;

    const int q0 = u * 32;
    const int nt = (u >> 1) + 1;

    // Q fragments (B-operand): col=q=q0+mt*16+lo, k=ks*32+hi*8+j
    bf16x8 qf[2][2];
#pragma unroll
    for (int mt = 0; mt < 2; ++mt)
#pragma unroll
        for (int ks = 0; ks < 2; ++ks)
            qf[mt][ks] = *reinterpret_cast<const bf16x8*>(
                &Qg[(size_t)(q0 + mt * 16 + lo) * HD_ + ks * 32 + hi * 8]);

    f32x4 o[2][4];
#pragma unroll
    for (int mt = 0; mt < 2; ++mt)
#pragma unroll
        for (int dt = 0; dt < 4; ++dt) o[mt][dt] = (f32x4){0.f, 0.f, 0.f, 0.f};
    float m_r[2] = {-INFINITY, -INFINITY};
    float l_r[2] = {0.f, 0.f};

    auto kload = [&](bf16x8 (&kf)[4][2], int kt) {
        const unsigned short* base = Kg + (size_t)kt * 64 * HD_;
#pragma unroll
        for (int ct = 0; ct < 4; ++ct)
#pragma unroll
            for (int ks = 0; ks < 2; ++ks)
                kf[ct][ks] = *reinterpret_cast<const bf16x8*>(
                    &base[(ct * 16 + lo) * HD_ + ks * 32 + hi * 8]);
    };

    // ===== body: EXACT R2 attn_fwd2 tile body (passed bit-level validation)
    auto body = [&](bf16x8 (&kf)[4][2], int kt) {
        const int kv0 = kt * 64;

        // V^T fragments for PV
        short4v vf[4][4];
#pragma unroll
        for (int dt = 0; dt < 4; ++dt)
#pragma unroll
            for (int ct = 0; ct < 4; ++ct)
                vf[dt][ct] = *reinterpret_cast<const short4v*>(
                    &Vg[(size_t)(dt * 16 + lo) * T_ + kv0 + ct * 16 + hi * 4]);

        // additive mask values
        f32x4 amv[4];
#pragma unroll
        for (int ct = 0; ct < 4; ++ct)
            amv[ct] = *reinterpret_cast<const f32x4*>(&am[kv0 + ct * 16 + hi * 4]);

        // S^T = K Q^T : lane holds S[kv0+ct*16+hi*4+r][q0+mt*16+lo]
        f32x4 s[2][4];
#pragma unroll
        for (int mt = 0; mt < 2; ++mt)
#pragma unroll
            for (int ct = 0; ct < 4; ++ct) s[mt][ct] = (f32x4){0.f, 0.f, 0.f, 0.f};
#pragma unroll
        for (int ks = 0; ks < 2; ++ks)
#pragma unroll
            for (int ct = 0; ct < 4; ++ct)
#pragma unroll
                for (int mt = 0; mt < 2; ++mt)
                    s[mt][ct] = __builtin_amdgcn_mfma_f32_16x16x32_bf16(
                        kf[ct][ks], qf[mt][ks], s[mt][ct], 0, 0, 0);

        const bool edge = (kv0 + 63 > q0);

        short4v p[2][4];
#pragma unroll
        for (int mt = 0; mt < 2; ++mt) {
            const int q = q0 + mt * 16 + lo;
            float mx = -INFINITY;
#pragma unroll
            for (int ct = 0; ct < 4; ++ct) {
#pragma unroll
                for (int r = 0; r < 4; ++r) {
                    float v = s[mt][ct][r] * SC + amv[ct][r] * LOG2E;
                    if (edge && (kv0 + ct * 16 + hi * 4 + r > q)) v = -INFINITY;
                    s[mt][ct][r] = v;
                    mx = fmaxf(mx, v);
                }
            }
            mx = fmaxf(mx, __shfl_xor(mx, 16, 64));
            mx = fmaxf(mx, __shfl_xor(mx, 32, 64));
            const float mnew = fmaxf(m_r[mt], mx);
            const float corr = exp2f(m_r[mt] - mnew);
            float rs = 0.f;
#pragma unroll
            for (int ct = 0; ct < 4; ++ct) {
                short4v pk;
#pragma unroll
                for (int r = 0; r < 4; ++r) {
                    float pe = exp2f(s[mt][ct][r] - mnew);
                    rs += pe;
                    pk[r] = (short)f2bf(pe);
                }
                p[mt][ct] = pk;
            }
            rs += __shfl_xor(rs, 16, 64);
            rs += __shfl_xor(rs, 32, 64);
            m_r[mt] = mnew;
            l_r[mt] = l_r[mt] * corr + rs;
#pragma unroll
            for (int dt = 0; dt < 4; ++dt) o[mt][dt] *= corr;
        }

        // O^T += V^T P^T
#pragma unroll
        for (int ct = 0; ct < 4; ++ct)
#pragma unroll
            for (int mt = 0; mt < 2; ++mt)
#pragma unroll
                for (int dt = 0; dt < 4; ++dt)
                    o[mt][dt] = mfma16x16x16bf16(vf[dt][ct], p[mt][ct], o[mt][dt]);
    };

    // ping-pong over kv tiles with depth-1 K prefetch (static buffers)
    bf16x8 kfA[4][2], kfB[4][2];
    kload(kfA, 0);
    int kt = 0;
    for (;;) {
        if (kt + 1 < nt) kload(kfB, kt + 1);
        body(kfA, kt);
        if (++kt == nt) break;
        if (kt + 1 < nt) kload(kfA, kt + 1);
        body(kfB, kt);
        if (++kt == nt) break;
    }

    // epilogue: out[tq][h*64+d] = O^T[d][q] / l[q]
#pragma unroll
    for (int mt = 0; mt < 2; ++mt) {
        const int tq = q0 + mt * 16 + lo;
        const float inv = 1.0f / l_r[mt];
        float* orow = outBase + (size_t)tq * H_;
#pragma unroll
        for (int dt = 0; dt < 4; ++dt) {
            f32x4 v = o[mt][dt] * inv;
            *reinterpret_cast<f32x4*>(&orow[dt * 16 + hi * 4]) = v;
        }
    }
}

// Grid: 1024 blocks x 128 threads (2 waves). Each XCD owns 8 heads.
__global__ __launch_bounds__(128, 2) void attn_fwd4(
    const unsigned short* __restrict__ Q,
    const unsigned short* __restrict__ Kb,
    const unsigned short* __restrict__ Vt,
    const float* __restrict__ amask,
    float* __restrict__ out)
{
    const int lane = threadIdx.x & 63;
    const int w    = threadIdx.x >> 6;          // 0..1
    const int lo = lane & 15, hi = lane >> 4;

    const int bid    = blockIdx.x;
    const int xcd    = bid & 7;
    const int within = bid >> 3;                // 0..127
    const int bh     = xcd * 8 + (within & 7);  // 8 heads per XCD
    const int s      = within >> 3;             // 0..15
    const int b      = bh >> 4;
    const int h      = bh & 15;

    const unsigned short* Qg = Q  + (size_t)bh * T_ * HD_;
    const unsigned short* Kg = Kb + (size_t)bh * T_ * HD_;
    const unsigned short* Vg = Vt + (size_t)bh * HD_ * T_;
    const float* am = amask + (size_t)b * T_;
    float* outBase = out + (size_t)b * T_ * H_ + h * HD_;

    const int u1 = s * 2 + w;        // 0..31
    const int u2 = 63 - u1;          // 32..63
    attn_unit(u1, lo, hi, Qg, Kg, Vg, am, outBase);
    attn_unit(u2, lo, hi, Qg, Kg, Vg, am, outBase);
}

// ---------------------------------------------------------------------------
extern "C" void kernel_launch(void* const* d_in, const int* in_sizes, int n_in,
                              void* d_out, int out_size, void* d_ws, size_t ws_size,
                              hipStream_t stream) {
    const float* hs    = (const float*)d_in[0];
    const float* amask = (const float*)d_in[1];
    const float* Wq    = (const float*)d_in[2];
    const float* bq    = (const float*)d_in[3];
    const float* Wk    = (const float*)d_in[4];
    const float* bk    = (const float*)d_in[5];
    const float* Wv    = (const float*)d_in[6];
    const float* bv    = (const float*)d_in[7];
    float* out = (float*)d_out;

    unsigned short* Xbf = (unsigned short*)d_ws;
    unsigned short* Wqb = Xbf + (size_t)8192 * 1024;
    unsigned short* Wkb = Wqb + (size_t)1024 * 1024;
    unsigned short* Wvb = Wkb + (size_t)1024 * 1024;
    unsigned short* Qb  = Wvb + (size_t)1024 * 1024;
    unsigned short* Kbf = Qb  + (size_t)B_ * NH_ * T_ * HD_;
    unsigned short* Vtb = Kbf + (size_t)B_ * NH_ * T_ * HD_;

    cvt_f32_bf16<<<4096, 256, 0, stream>>>(hs, Xbf, (8192 * 1024) / 8);
    cvt_f32_bf16<<<512, 256, 0, stream>>>(Wq, Wqb, (1024 * 1024) / 8);
    cvt_f32_bf16<<<512, 256, 0, stream>>>(Wk, Wkb, (1024 * 1024) / 8);
    cvt_f32_bf16<<<512, 256, 0, stream>>>(Wv, Wvb, (1024 * 1024) / 8);

    dim3 g(8, 64);
    qkv_gemm<0><<<g, 256, 0, stream>>>(Xbf, Wqb, bq, Qb);
    qkv_gemm<0><<<g, 256, 0, stream>>>(Xbf, Wkb, bk, Kbf);
    qkv_gemm<2><<<g, 256, 0, stream>>>(Xbf, Wvb, bv, Vtb);

    attn_fwd4<<<1024, 128, 0, stream>>>(Qb, Kbf, Vtb, amask, out);
}

// Round 5
// 305.183 us; speedup vs baseline: 1.2916x; 1.0754x over previous
//
#include <hip/hip_runtime.h>
#include <math.h>

// Problem constants
#define B_  4
#define T_  2048
#define H_  1024
#define NH_ 16
#define HD_ 64

typedef __bf16  bf16x8  __attribute__((ext_vector_type(8)));
typedef float   f32x4   __attribute__((ext_vector_type(4)));
typedef unsigned short ushort8v __attribute__((ext_vector_type(8)));
typedef short   short4v __attribute__((ext_vector_type(4)));

__device__ __forceinline__ unsigned short f2bf(float f) {
    unsigned int u = __builtin_bit_cast(unsigned int, f);
    u += 0x7fffu + ((u >> 16) & 1u);
    return (unsigned short)(u >> 16);
}

// 16x16x16 bf16 MFMA (K=16): A/B k=(lane>>4)*4+j
__device__ __forceinline__ f32x4 mfma16x16x16bf16(short4v a, short4v b, f32x4 c) {
#if __has_builtin(__builtin_amdgcn_mfma_f32_16x16x16bf16_1k)
    return __builtin_amdgcn_mfma_f32_16x16x16bf16_1k(a, b, c, 0, 0, 0);
#else
    f32x4 d = c;
    asm volatile("v_mfma_f32_16x16x16_bf16 %0, %1, %2, %0\n\ts_nop 7\n\ts_nop 7"
                 : "+v"(d) : "v"(a), "v"(b));
    return d;
#endif
}

// ---------------------------------------------------------------------------
__global__ void cvt_f32_bf16(const float* __restrict__ in,
                             unsigned short* __restrict__ out, int n8) {
    int stride = gridDim.x * blockDim.x;
    for (int i = blockIdx.x * blockDim.x + threadIdx.x; i < n8; i += stride) {
        const float4* p = reinterpret_cast<const float4*>(in) + (size_t)i * 2;
        float4 f0 = p[0], f1 = p[1];
        ushort8v o;
        o[0] = f2bf(f0.x); o[1] = f2bf(f0.y); o[2] = f2bf(f0.z); o[3] = f2bf(f0.w);
        o[4] = f2bf(f1.x); o[5] = f2bf(f1.y); o[6] = f2bf(f1.z); o[7] = f2bf(f1.w);
        reinterpret_cast<ushort8v*>(out)[i] = o;
    }
}

// ---------------------------------------------------------------------------
// QKV projection GEMM (unchanged from R2/R4)
template <int MODE>
__global__ __launch_bounds__(256) void qkv_gemm(
    const unsigned short* __restrict__ X,
    const unsigned short* __restrict__ W,
    const float* __restrict__ bias,
    unsigned short* __restrict__ out)
{
    const int K = 1024;
    const int t    = threadIdx.x;
    const int lane = t & 63;
    const int wid  = t >> 6;
    const int lo = lane & 15, hi = lane >> 4;
    const int wm = wid >> 1, wn = wid & 1;
    const int m0 = blockIdx.y * 128;
    const int n0 = blockIdx.x * 128;

    __shared__ unsigned short As[128 * 72];
    __shared__ unsigned short Bs[128 * 72];

    f32x4 acc[4][4];
#pragma unroll
    for (int i = 0; i < 4; ++i)
#pragma unroll
        for (int j = 0; j < 4; ++j) acc[i][j] = (f32x4){0.f, 0.f, 0.f, 0.f};

    for (int k0 = 0; k0 < K; k0 += 64) {
        __syncthreads();
#pragma unroll
        for (int p = 0; p < 4; ++p) {
            int idx = (p * 256 + t) * 8;
            int row = idx >> 6, col = idx & 63;
            *reinterpret_cast<ushort8v*>(&As[row * 72 + col]) =
                *reinterpret_cast<const ushort8v*>(&X[(size_t)(m0 + row) * K + k0 + col]);
            *reinterpret_cast<ushort8v*>(&Bs[row * 72 + col]) =
                *reinterpret_cast<const ushort8v*>(&W[(size_t)(n0 + row) * K + k0 + col]);
        }
        __syncthreads();
#pragma unroll
        for (int ks = 0; ks < 2; ++ks) {
            bf16x8 a[4], b[4];
#pragma unroll
            for (int mt = 0; mt < 4; ++mt)
                a[mt] = *reinterpret_cast<const bf16x8*>(
                    &As[(wm * 64 + mt * 16 + lo) * 72 + ks * 32 + hi * 8]);
#pragma unroll
            for (int nt = 0; nt < 4; ++nt)
                b[nt] = *reinterpret_cast<const bf16x8*>(
                    &Bs[(wn * 64 + nt * 16 + lo) * 72 + ks * 32 + hi * 8]);
#pragma unroll
            for (int mt = 0; mt < 4; ++mt)
#pragma unroll
                for (int nt = 0; nt < 4; ++nt)
                    acc[mt][nt] = __builtin_amdgcn_mfma_f32_16x16x32_bf16(
                        a[mt], b[nt], acc[mt][nt], 0, 0, 0);
        }
    }

#pragma unroll
    for (int nt = 0; nt < 4; ++nt) {
        int n = n0 + wn * 64 + nt * 16 + lo;
        float bv = bias[n];
        int h = n >> 6, d = n & 63;
#pragma unroll
        for (int mt = 0; mt < 4; ++mt) {
            int mbase = m0 + wm * 64 + mt * 16 + hi * 4;
            int bb = mbase >> 11;
            int tt = mbase & 2047;
            if (MODE == 2) {
                ushort4 pk;
                pk.x = f2bf(acc[mt][nt][0] + bv);
                pk.y = f2bf(acc[mt][nt][1] + bv);
                pk.z = f2bf(acc[mt][nt][2] + bv);
                pk.w = f2bf(acc[mt][nt][3] + bv);
                size_t addr = ((size_t)(bb * NH_ + h) * HD_ + d) * T_ + tt;
                *reinterpret_cast<ushort4*>(&out[addr]) = pk;
            } else {
                size_t base = (size_t)(bb * NH_ + h) * T_;
#pragma unroll
                for (int r = 0; r < 4; ++r)
                    out[(base + tt + r) * HD_ + d] = f2bf(acc[mt][nt][r] + bv);
            }
        }
    }
}

// ---------------------------------------------------------------------------
// Causal flash attention v5: kv-split across 2 waves + LDS merge.
// One block (128 thr) per (bh, u): unit u = 32 q-rows. Wave 0 does kv tiles
// [0, nt/2), wave 1 does [nt/2, nt); merge (m, l, O) through LDS at the end.
// Tile body is the R2/R4-proven code, unchanged.
__global__ __launch_bounds__(128, 4) void attn_fwd5(
    const unsigned short* __restrict__ Q,
    const unsigned short* __restrict__ Kb,
    const unsigned short* __restrict__ Vt,
    const float* __restrict__ amask,
    float* __restrict__ out)
{
    const float SC    = 0.125f * 1.44269504089f;
    const float LOG2E = 1.44269504089f;

    const int lane = threadIdx.x & 63;
    const int w    = threadIdx.x >> 6;          // 0..1
    const int lo = lane & 15, hi = lane >> 4;

    // decode: 8 heads per XCD; long units (u near 63) dispatched first
    const int bid    = blockIdx.x;
    const int xcd    = bid & 7;
    const int within = bid >> 3;                // 0..511
    const int bh     = xcd * 8 + (within & 7);
    const int u      = 63 - (within >> 3);      // 63..0 (longest first)
    const int b      = bh >> 4;
    const int h      = bh & 15;

    const unsigned short* Qg = Q  + (size_t)bh * T_ * HD_;
    const unsigned short* Kg = Kb + (size_t)bh * T_ * HD_;
    const unsigned short* Vg = Vt + (size_t)bh * HD_ * T_;
    const float* am = amask + (size_t)b * T_;

    const int q0   = u * 32;
    const int nt   = (u >> 1) + 1;
    const int half = nt >> 1;
    const int ktBeg = w ? half : 0;
    const int ktEnd = w ? nt : half;

    // LDS for the cross-wave merge: [mt][dt][lane] f32x4 + m/l arrays
    __shared__ f32x4 Lo[2][4][64];
    __shared__ float Lm[2][64];
    __shared__ float Ll[2][64];

    // Q fragments (B-operand): col=q=q0+mt*16+lo, k=ks*32+hi*8+j
    bf16x8 qf[2][2];
#pragma unroll
    for (int mt = 0; mt < 2; ++mt)
#pragma unroll
        for (int ks = 0; ks < 2; ++ks)
            qf[mt][ks] = *reinterpret_cast<const bf16x8*>(
                &Qg[(size_t)(q0 + mt * 16 + lo) * HD_ + ks * 32 + hi * 8]);

    f32x4 o[2][4];
#pragma unroll
    for (int mt = 0; mt < 2; ++mt)
#pragma unroll
        for (int dt = 0; dt < 4; ++dt) o[mt][dt] = (f32x4){0.f, 0.f, 0.f, 0.f};
    float m_r[2] = {-INFINITY, -INFINITY};
    float l_r[2] = {0.f, 0.f};

    for (int kt = ktBeg; kt < ktEnd; ++kt) {
        const int kv0 = kt * 64;

        // K fragments: row=kv=ct*16+lo, k=ks*32+hi*8+j
        bf16x8 kf[4][2];
#pragma unroll
        for (int ct = 0; ct < 4; ++ct)
#pragma unroll
            for (int ks = 0; ks < 2; ++ks)
                kf[ct][ks] = *reinterpret_cast<const bf16x8*>(
                    &Kg[(size_t)(kv0 + ct * 16 + lo) * HD_ + ks * 32 + hi * 8]);

        // V^T fragments for PV (issued early; consumed after softmax)
        short4v vf[4][4];
#pragma unroll
        for (int dt = 0; dt < 4; ++dt)
#pragma unroll
            for (int ct = 0; ct < 4; ++ct)
                vf[dt][ct] = *reinterpret_cast<const short4v*>(
                    &Vg[(size_t)(dt * 16 + lo) * T_ + kv0 + ct * 16 + hi * 4]);

        // additive mask values
        f32x4 amv[4];
#pragma unroll
        for (int ct = 0; ct < 4; ++ct)
            amv[ct] = *reinterpret_cast<const f32x4*>(&am[kv0 + ct * 16 + hi * 4]);

        // S^T = K Q^T : lane holds S[kv0+ct*16+hi*4+r][q0+mt*16+lo]
        f32x4 s[2][4];
#pragma unroll
        for (int mt = 0; mt < 2; ++mt)
#pragma unroll
            for (int ct = 0; ct < 4; ++ct) s[mt][ct] = (f32x4){0.f, 0.f, 0.f, 0.f};
#pragma unroll
        for (int ks = 0; ks < 2; ++ks)
#pragma unroll
            for (int ct = 0; ct < 4; ++ct)
#pragma unroll
                for (int mt = 0; mt < 2; ++mt)
                    s[mt][ct] = __builtin_amdgcn_mfma_f32_16x16x32_bf16(
                        kf[ct][ks], qf[mt][ks], s[mt][ct], 0, 0, 0);

        const bool edge = (kv0 + 63 > q0);

        short4v p[2][4];
#pragma unroll
        for (int mt = 0; mt < 2; ++mt) {
            const int q = q0 + mt * 16 + lo;
            float mx = -INFINITY;
#pragma unroll
            for (int ct = 0; ct < 4; ++ct) {
#pragma unroll
                for (int r = 0; r < 4; ++r) {
                    float v = s[mt][ct][r] * SC + amv[ct][r] * LOG2E;
                    if (edge && (kv0 + ct * 16 + hi * 4 + r > q)) v = -INFINITY;
                    s[mt][ct][r] = v;
                    mx = fmaxf(mx, v);
                }
            }
            mx = fmaxf(mx, __shfl_xor(mx, 16, 64));
            mx = fmaxf(mx, __shfl_xor(mx, 32, 64));
            const float mnew = fmaxf(m_r[mt], mx);
            const float corr = exp2f(m_r[mt] - mnew);
            float rs = 0.f;
#pragma unroll
            for (int ct = 0; ct < 4; ++ct) {
                short4v pk;
#pragma unroll
                for (int r = 0; r < 4; ++r) {
                    float pe = exp2f(s[mt][ct][r] - mnew);
                    rs += pe;
                    pk[r] = (short)f2bf(pe);
                }
                p[mt][ct] = pk;
            }
            rs += __shfl_xor(rs, 16, 64);
            rs += __shfl_xor(rs, 32, 64);
            m_r[mt] = mnew;
            l_r[mt] = l_r[mt] * corr + rs;
#pragma unroll
            for (int dt = 0; dt < 4; ++dt) o[mt][dt] *= corr;
        }

        // O^T += V^T P^T
#pragma unroll
        for (int ct = 0; ct < 4; ++ct)
#pragma unroll
            for (int mt = 0; mt < 2; ++mt)
#pragma unroll
                for (int dt = 0; dt < 4; ++dt)
                    o[mt][dt] = mfma16x16x16bf16(vf[dt][ct], p[mt][ct], o[mt][dt]);
    }

    // ---- merge: wave 1 publishes, wave 0 combines and writes out ----
    if (w == 1) {
#pragma unroll
        for (int mt = 0; mt < 2; ++mt) {
            Lm[mt][lane] = m_r[mt];
            Ll[mt][lane] = l_r[mt];
#pragma unroll
            for (int dt = 0; dt < 4; ++dt)
                Lo[mt][dt][lane] = o[mt][dt];
        }
    }
    __syncthreads();
    if (w == 0) {
        float* outBase = out + (size_t)b * T_ * H_ + h * HD_;
#pragma unroll
        for (int mt = 0; mt < 2; ++mt) {
            const float mB = Lm[mt][lane];
            const float lB = Ll[mt][lane];
            const float m  = fmaxf(m_r[mt], mB);
            const float cA = exp2f(m_r[mt] - m);   // 0 if this half was empty
            const float cB = exp2f(mB - m);
            const float l  = l_r[mt] * cA + lB * cB;
            const float inv = 1.0f / l;
            const int tq = q0 + mt * 16 + lo;
            float* orow = outBase + (size_t)tq * H_;
#pragma unroll
            for (int dt = 0; dt < 4; ++dt) {
                f32x4 oB = Lo[mt][dt][lane];
                f32x4 v = (o[mt][dt] * cA + oB * cB) * inv;
                *reinterpret_cast<f32x4*>(&orow[dt * 16 + hi * 4]) = v;
            }
        }
    }
}

// ---------------------------------------------------------------------------
extern "C" void kernel_launch(void* const* d_in, const int* in_sizes, int n_in,
                              void* d_out, int out_size, void* d_ws, size_t ws_size,
                              hipStream_t stream) {
    const float* hs    = (const float*)d_in[0];
    const float* amask = (const float*)d_in[1];
    const float* Wq    = (const float*)d_in[2];
    const float* bq    = (const float*)d_in[3];
    const float* Wk    = (const float*)d_in[4];
    const float* bk    = (const float*)d_in[5];
    const float* Wv    = (const float*)d_in[6];
    const float* bv    = (const float*)d_in[7];
    float* out = (float*)d_out;

    unsigned short* Xbf = (unsigned short*)d_ws;
    unsigned short* Wqb = Xbf + (size_t)8192 * 1024;
    unsigned short* Wkb = Wqb + (size_t)1024 * 1024;
    unsigned short* Wvb = Wkb + (size_t)1024 * 1024;
    unsigned short* Qb  = Wvb + (size_t)1024 * 1024;
    unsigned short* Kbf = Qb  + (size_t)B_ * NH_ * T_ * HD_;
    unsigned short* Vtb = Kbf + (size_t)B_ * NH_ * T_ * HD_;

    cvt_f32_bf16<<<4096, 256, 0, stream>>>(hs, Xbf, (8192 * 1024) / 8);
    cvt_f32_bf16<<<512, 256, 0, stream>>>(Wq, Wqb, (1024 * 1024) / 8);
    cvt_f32_bf16<<<512, 256, 0, stream>>>(Wk, Wkb, (1024 * 1024) / 8);
    cvt_f32_bf16<<<512, 256, 0, stream>>>(Wv, Wvb, (1024 * 1024) / 8);

    dim3 g(8, 64);
    qkv_gemm<0><<<g, 256, 0, stream>>>(Xbf, Wqb, bq, Qb);
    qkv_gemm<0><<<g, 256, 0, stream>>>(Xbf, Wkb, bk, Kbf);
    qkv_gemm<2><<<g, 256, 0, stream>>>(Xbf, Wvb, bv, Vtb);

    attn_fwd5<<<4096, 128, 0, stream>>>(Qb, Kbf, Vtb, amask, out);
}